// Round 6
// baseline (112.332 us; speedup 1.0000x reference)
//
#include <hip/hip_runtime.h>

#define T0 4096
#define N1 2051          // level-1 output length
#define N2 1029
#define N3 518
#define N4 262
#define N5 134
#define BLOCK 256
#define PAD 6            // left pad; right pad is 7

// filters reversed so tap k multiplies ext[2i+k]  (rLO[k] = DEC_LO[7-k])
#define RLO0  0.23037781330885523f
#define RLO1  0.7148465705525415f
#define RLO2  0.6308807679295904f
#define RLO3 -0.02798376941698385f
#define RLO4 -0.18703481171888114f
#define RLO5  0.030841381835986965f
#define RLO6  0.032883011666982945f
#define RLO7 -0.010597401784997278f

#define RHI0 -0.010597401784997278f
#define RHI1 -0.032883011666982945f
#define RHI2  0.030841381835986965f
#define RHI3  0.18703481171888114f
#define RHI4 -0.02798376941698385f
#define RHI5 -0.6308807679295904f
#define RHI6  0.7148465705525415f
#define RHI7 -0.23037781330885523f

__device__ __forceinline__ int symidx(int t, int L) {
    t = (t < 0) ? (-1 - t) : t;
    t = (t >= L) ? (2 * L - 1 - t) : t;
    return t;
}

__device__ __forceinline__ void filt8(const float* __restrict__ t,
                                      float& lo, float& hi) {
    lo = RLO0 * t[0];            hi = RHI0 * t[0];
    lo = fmaf(RLO1, t[1], lo);   hi = fmaf(RHI1, t[1], hi);
    lo = fmaf(RLO2, t[2], lo);   hi = fmaf(RHI2, t[2], hi);
    lo = fmaf(RLO3, t[3], lo);   hi = fmaf(RHI3, t[3], hi);
    lo = fmaf(RLO4, t[4], lo);   hi = fmaf(RHI4, t[4], hi);
    lo = fmaf(RLO5, t[5], lo);   hi = fmaf(RHI5, t[5], hi);
    lo = fmaf(RLO6, t[6], lo);   hi = fmaf(RHI6, t[6], hi);
    lo = fmaf(RLO7, t[7], lo);   hi = fmaf(RHI7, t[7], hi);
}

__global__ __launch_bounds__(BLOCK) void dwt5_kernel(
    const float* __restrict__ x, float* __restrict__ out,
    long long offA, long long offD1, long long offD2, long long offD3,
    long long offD4, long long offD5)
{
    __shared__ float extB[N1 + 16];    // L1 approx (2051), reused for L3 out (518)
    __shared__ float extC[N2 + 16];    // L2 out (1029), reused for L4 out (262)

    const int row = blockIdx.x;
    const int tid = threadIdx.x;
    const float* __restrict__ xrow = x + (size_t)row * T0;

    // ================= level 1: 8 lane-consecutive outputs/thread ============
    float2 t[8][4];
    {
        const int b0 = (tid >= 3) ? (2 * tid - 6) : 0;   // clamp lanes 0..2
        const float2* __restrict__ p = reinterpret_cast<const float2*>(xrow + b0);
#pragma unroll
        for (int q = 0; q < 4; ++q) t[0][q] = p[q];
    }
#pragma unroll
    for (int k = 1; k < 8; ++k) {
        const float2* __restrict__ p =
            reinterpret_cast<const float2*>(xrow + 2 * (tid + 256 * k) - 6);
#pragma unroll
        for (int q = 0; q < 4; ++q) t[k][q] = p[q];
    }

    float d1r[8];                       // deferred d1 stores
#pragma unroll
    for (int k = 0; k < 8; ++k) {
        const int i = tid + 256 * k;    // 0..2047
        const float tt[8] = {t[k][0].x, t[k][0].y, t[k][1].x, t[k][1].y,
                             t[k][2].x, t[k][2].y, t[k][3].x, t[k][3].y};
        float lo, hi;
        filt8(tt, lo, hi);
        d1r[k] = hi;
        extB[PAD + i] = lo;
        if (i < 6)       extB[5 - i] = lo;                    // left mirror
        if (i >= N1 - 7) extB[PAD + N1 + (N1 - 1 - i)] = lo;  // right mirror
    }

    // fix-ups by tid<3: outputs 0..2 and 2048..2050 (hi deferred to regs)
    float fixL = 0.f, fixR = 0.f;
    if (tid < 3) {
        {
            const int i = tid;
            float tt[8];
#pragma unroll
            for (int k = 0; k < 8; ++k) tt[k] = xrow[symidx(2 * i - 6 + k, T0)];
            float lo;
            filt8(tt, lo, fixL);
            extB[PAD + i] = lo;
            extB[5 - i] = lo;
        }
        {
            const int i = 2048 + tid;
            float tt[8];
#pragma unroll
            for (int k = 0; k < 8; ++k) tt[k] = xrow[symidx(2 * i - 6 + k, T0)];
            float lo;
            filt8(tt, lo, fixR);
            extB[PAD + i] = lo;
            extB[PAD + N1 + (N1 - 1 - i)] = lo;
        }
    }
    __syncthreads();

    // ================= level 2: extB -> extC, hi -> r2[5] ====================
    float r2[5];
    {
        const float2* __restrict__ e2 = reinterpret_cast<const float2*>(extB);
#pragma unroll
        for (int s = 0; s < 5; ++s) {
            const int i = tid + 256 * s;
            if (s < 4 || tid < 5) {          // i < 1029
                const float2 w0 = e2[i], w1 = e2[i + 1], w2 = e2[i + 2], w3 = e2[i + 3];
                const float tt[8] = {w0.x, w0.y, w1.x, w1.y, w2.x, w2.y, w3.x, w3.y};
                float lo, hi;
                filt8(tt, lo, hi);
                r2[s] = hi;
                extC[PAD + i] = lo;
                if (i < 6)       extC[5 - i] = lo;
                if (i >= N2 - 7) extC[PAD + N2 + (N2 - 1 - i)] = lo;
            }
        }
    }
    __syncthreads();

    // ================= level 3: extC -> extB, hi -> r3[3] ====================
    float r3[3];
    {
        const float2* __restrict__ e2 = reinterpret_cast<const float2*>(extC);
#pragma unroll
        for (int s = 0; s < 3; ++s) {
            const int i = tid + 256 * s;
            if (s < 2 || tid < 6) {          // i < 518
                const float2 w0 = e2[i], w1 = e2[i + 1], w2 = e2[i + 2], w3 = e2[i + 3];
                const float tt[8] = {w0.x, w0.y, w1.x, w1.y, w2.x, w2.y, w3.x, w3.y};
                float lo, hi;
                filt8(tt, lo, hi);
                r3[s] = hi;
                extB[PAD + i] = lo;
                if (i < 6)       extB[5 - i] = lo;
                if (i >= N3 - 7) extB[PAD + N3 + (N3 - 1 - i)] = lo;
            }
        }
    }
    __syncthreads();

    // ================= level 4: extB -> extC, hi -> r4[2] ====================
    float r4[2];
    {
        const float2* __restrict__ e2 = reinterpret_cast<const float2*>(extB);
#pragma unroll
        for (int s = 0; s < 2; ++s) {
            const int i = tid + 256 * s;
            if (s < 1 || tid < 6) {          // i < 262
                const float2 w0 = e2[i], w1 = e2[i + 1], w2 = e2[i + 2], w3 = e2[i + 3];
                const float tt[8] = {w0.x, w0.y, w1.x, w1.y, w2.x, w2.y, w3.x, w3.y};
                float lo, hi;
                filt8(tt, lo, hi);
                r4[s] = hi;
                extC[PAD + i] = lo;
                if (i < 6)       extC[5 - i] = lo;
                if (i >= N4 - 7) extC[PAD + N4 + (N4 - 1 - i)] = lo;
            }
        }
    }
    __syncthreads();

    // ================= level 5: extC -> regs (d5 + approx) ==================
    float r5 = 0.f, rA = 0.f;
    if (tid < N5) {
        const float2* __restrict__ e2 = reinterpret_cast<const float2*>(extC);
        const int i = tid;
        const float2 w0 = e2[i], w1 = e2[i + 1], w2 = e2[i + 2], w3 = e2[i + 3];
        const float tt[8] = {w0.x, w0.y, w1.x, w1.y, w2.x, w2.y, w3.x, w3.y};
        filt8(tt, rA, r5);
    }

    // ================= final store burst (fire-and-forget) ==================
    float* __restrict__ d1 = out + offD1 + (long long)row * N1;
    float* __restrict__ d2 = out + offD2 + (long long)row * N2;
    float* __restrict__ d3 = out + offD3 + (long long)row * N3;
    float* __restrict__ d4 = out + offD4 + (long long)row * N4;
    float* __restrict__ d5 = out + offD5 + (long long)row * N5;
    float* __restrict__ aO = out + offA  + (long long)row * N5;

#pragma unroll
    for (int k = 0; k < 8; ++k) {
        const int i = tid + 256 * k;
        if (k > 0 || tid >= 3)
            __builtin_nontemporal_store(d1r[k], &d1[i]);
    }
    if (tid < 3) {
        __builtin_nontemporal_store(fixL, &d1[tid]);
        __builtin_nontemporal_store(fixR, &d1[2048 + tid]);
    }
#pragma unroll
    for (int s = 0; s < 5; ++s) {
        const int i = tid + 256 * s;
        if (s < 4 || tid < 5) __builtin_nontemporal_store(r2[s], &d2[i]);
    }
#pragma unroll
    for (int s = 0; s < 3; ++s) {
        const int i = tid + 256 * s;
        if (s < 2 || tid < 6) __builtin_nontemporal_store(r3[s], &d3[i]);
    }
#pragma unroll
    for (int s = 0; s < 2; ++s) {
        const int i = tid + 256 * s;
        if (s < 1 || tid < 6) __builtin_nontemporal_store(r4[s], &d4[i]);
    }
    if (tid < N5) {
        __builtin_nontemporal_store(r5, &d5[tid]);
        __builtin_nontemporal_store(rA, &aO[tid]);
    }
}

extern "C" void kernel_launch(void* const* d_in, const int* in_sizes, int n_in,
                              void* d_out, int out_size, void* d_ws, size_t ws_size,
                              hipStream_t stream) {
    const float* x = (const float*)d_in[0];
    float* out = (float*)d_out;

    const int rows = in_sizes[0] / T0;   // 64*64 = 4096

    const long long offA  = 0;
    const long long offD5 = offA  + (long long)rows * N5;
    const long long offD4 = offD5 + (long long)rows * N5;
    const long long offD3 = offD4 + (long long)rows * N4;
    const long long offD2 = offD3 + (long long)rows * N3;
    const long long offD1 = offD2 + (long long)rows * N2;

    dwt5_kernel<<<rows, BLOCK, 0, stream>>>(x, out, offA, offD1, offD2, offD3,
                                            offD4, offD5);
}